// Round 12
// baseline (170.095 us; speedup 1.0000x reference)
//
#include <hip/hip_runtime.h>
#include <math.h>

#define BATCHN 65536
#define INPUTN 128
#define HIDDENN 512
#define CATN 640

typedef float f2v __attribute__((ext_vector_type(2)));
typedef float f4v __attribute__((ext_vector_type(4)));
typedef short s8v __attribute__((ext_vector_type(8)));

__device__ __forceinline__ unsigned short f2bf_rne(float f) {
  unsigned u = __float_as_uint(f);
  u += 0x7fffu + ((u >> 16) & 1u);
  return (unsigned short)(u >> 16);
}

// pack 8 fp32 -> 8 bf16 (RNE) in MFMA fragment order
__device__ __forceinline__ s8v pack_bf16x8(float4 lo, float4 hi) {
  union { s8v s; unsigned u[4]; } r;
  asm("v_cvt_pk_bf16_f32 %0, %1, %2" : "=v"(r.u[0]) : "v"(lo.x), "v"(lo.y));
  asm("v_cvt_pk_bf16_f32 %0, %1, %2" : "=v"(r.u[1]) : "v"(lo.z), "v"(lo.w));
  asm("v_cvt_pk_bf16_f32 %0, %1, %2" : "=v"(r.u[2]) : "v"(hi.x), "v"(hi.y));
  asm("v_cvt_pk_bf16_f32 %0, %1, %2" : "=v"(r.u[3]) : "v"(hi.z), "v"(hi.w));
  return r.s;
}

__device__ __forceinline__ float sigmf(float v) {
  return __builtin_amdgcn_rcpf(1.f + __expf(-v));
}
__device__ __forceinline__ float tanhfast(float v) {
  return 1.f - 2.f * __builtin_amdgcn_rcpf(__expf(2.f * v) + 1.f);
}

// ---------------------------------------------------------------------------
// Prologue (1 block): (a) threads 0..63 build the fixed 16x16 unitary U_g per
// gate; (b) pack projection weights into bf16 MFMA B-fragments in lane order:
// Bfrag[s][lane] = B[k = s*32 + (lane>>4)*8 + j][n = lane&15], where
// B[k][n] = pw_{gate=n>>2}[(n&3)*640 + k].  20 KB, L2-hot. (verified v10/v11)
// ---------------------------------------------------------------------------
__global__ void k_prologue(const float* __restrict__ qwF, const float* __restrict__ qwI,
                           const float* __restrict__ qwO, const float* __restrict__ qwC,
                           const float* __restrict__ pwF, const float* __restrict__ pwI,
                           const float* __restrict__ pwO, const float* __restrict__ pwC,
                           float2* __restrict__ U, unsigned short* __restrict__ Bfrag) {
  const int t = threadIdx.x;
  if (t < 64) {
    int g = t >> 4, col = t & 15;
    const float* qw = (g == 0) ? qwF : (g == 1) ? qwI : (g == 2) ? qwO : qwC;

    float sr[16], si[16];
#pragma unroll
    for (int i = 0; i < 16; i++) { sr[i] = (i == col) ? 1.f : 0.f; si[i] = 0.f; }

#pragma unroll
    for (int l = 0; l < 2; l++) {
#pragma unroll
      for (int j = 0; j < 4; j++) {
        const int bc = 8 >> j;
        const int bt = 8 >> ((j + 1) & 3);
        float tr[16], ti[16];
#pragma unroll
        for (int i = 0; i < 16; i++) {
          int src = (i & bc) ? (i ^ bt) : i;
          tr[i] = sr[src]; ti[i] = si[src];
        }
#pragma unroll
        for (int i = 0; i < 16; i++) { sr[i] = tr[i]; si[i] = ti[i]; }
      }
#pragma unroll
      for (int j = 0; j < 4; j++) {
        const int bit = 8 >> j;
        const float thx = qw[(l * 4 + j) * 3 + 0] * 0.5f;
        const float thy = qw[(l * 4 + j) * 3 + 1] * 0.5f;
        const float thz = qw[(l * 4 + j) * 3 + 2] * 0.5f;
        float c, s;
        c = cosf(thx); s = sinf(thx);           // RX
#pragma unroll
        for (int i = 0; i < 16; i++) if (!(i & bit)) {
          const int k2 = i | bit;
          const float ar = sr[i], ai = si[i], br = sr[k2], bi = si[k2];
          sr[i]  = c * ar + s * bi;  si[i]  = c * ai - s * br;
          sr[k2] = c * br + s * ai;  si[k2] = c * bi - s * ar;
        }
        c = cosf(thy); s = sinf(thy);           // RY
#pragma unroll
        for (int i = 0; i < 16; i++) if (!(i & bit)) {
          const int k2 = i | bit;
          const float ar = sr[i], ai = si[i], br = sr[k2], bi = si[k2];
          sr[i]  = c * ar - s * br;  si[i]  = c * ai - s * bi;
          sr[k2] = s * ar + c * br;  si[k2] = s * ai + c * bi;
        }
        c = cosf(thz); s = sinf(thz);           // RZ
#pragma unroll
        for (int i = 0; i < 16; i++) if (!(i & bit)) {
          const int k2 = i | bit;
          const float ar = sr[i], ai = si[i], br = sr[k2], bi = si[k2];
          sr[i]  = c * ar + s * ai;  si[i]  = c * ai - s * ar;
          sr[k2] = c * br - s * bi;  si[k2] = c * bi + s * br;
        }
      }
    }
#pragma unroll
    for (int m = 0; m < 16; m++)
      U[(g * 16 + m) * 16 + col] = make_float2(sr[m], si[m]);
  }

  // B fragments: 20 k-steps x 64 lanes
  for (int e = t; e < 20 * 64; e += 256) {
    const int s = e >> 6, l = e & 63;
    const int n = l & 15, kb = l >> 4;
    const int gate = n >> 2, orow = n & 3;
    const float* pw = (gate == 0) ? pwF : (gate == 1) ? pwI : (gate == 2) ? pwO : pwC;
    const int k0 = s * 32 + kb * 8;
    unsigned short* dst = Bfrag + (size_t)e * 8;
#pragma unroll
    for (int j = 0; j < 8; ++j) dst[j] = f2bf_rne(pw[orow * CATN + k0 + j]);
  }
}

// ---------------------------------------------------------------------------
// Fused kernel (v12): block = 64 rows.
// Phase 1 (v11, verified): MFMA proj with A-fragments direct from global,
//   B-fragments prepacked (L2-hot), no LDS staging, no main-loop barriers.
// Phase 2: angL exchange -> in-register quantum sim (thread = row,gate) ->
//   q into 5 KB LDS (replaces the 4 MB qv global round-trip).
// Phase 3: LSTM expansion for the SAME 64 rows (proven float2-NT pattern; q
//   reads are wave-uniform broadcast ds_reads).
// Fusion lets blocks at different phases overlap chip-wide: proj load latency
// hides under other blocks' lstm VALU + write streams.
// ---------------------------------------------------------------------------
__global__ __launch_bounds__(256, 4) void k_fused(
    const float* __restrict__ x, const float* __restrict__ hprev,
    const float* __restrict__ pbF, const float* __restrict__ pbI,
    const float* __restrict__ pbO, const float* __restrict__ pbC,
    const float2* __restrict__ U, const unsigned short* __restrict__ Bfrag,
    const float* __restrict__ cprev,
    const float* __restrict__ lwF, const float* __restrict__ lbF,
    const float* __restrict__ lwI, const float* __restrict__ lbI,
    const float* __restrict__ lwO, const float* __restrict__ lbO,
    const float* __restrict__ lwC, const float* __restrict__ lbC,
    float* __restrict__ out) {
  __shared__ float angL[64 * 17];
  __shared__ float qL[64 * 20];
  const int tid = threadIdx.x;
  const int lane = tid & 63;
  const int wv = tid >> 6;
  const int m0 = wv * 16;
  const size_t rb = (size_t)blockIdx.x * 64;

  // ---- Phase 1: MFMA projection (A direct from global) ----
  {
    const int mr = lane & 15;           // A row within wave tile
    const int kb = lane >> 4;           // k-block 0..3
    const size_t arow = rb + m0 + mr;

    f4v acc = {0.f, 0.f, 0.f, 0.f};

    const float* xr = x + arow * INPUTN + kb * 8;
#pragma unroll
    for (int T = 0; T < 2; ++T) {
      const float4 l0 = *(const float4*)(xr + T * 64);
      const float4 h0 = *(const float4*)(xr + T * 64 + 4);
      const float4 l1 = *(const float4*)(xr + T * 64 + 32);
      const float4 h1 = *(const float4*)(xr + T * 64 + 36);
      const s8v b0 = *(const s8v*)(Bfrag + ((size_t)(T * 2 + 0) * 64 + lane) * 8);
      const s8v b1 = *(const s8v*)(Bfrag + ((size_t)(T * 2 + 1) * 64 + lane) * 8);
      acc = __builtin_amdgcn_mfma_f32_16x16x32_bf16(pack_bf16x8(l0, h0), b0, acc, 0, 0, 0);
      acc = __builtin_amdgcn_mfma_f32_16x16x32_bf16(pack_bf16x8(l1, h1), b1, acc, 0, 0, 0);
    }
    const float* hr = hprev + arow * HIDDENN + kb * 8;
#pragma unroll 2
    for (int T = 0; T < 8; ++T) {
      const float4 l0 = *(const float4*)(hr + T * 64);
      const float4 h0 = *(const float4*)(hr + T * 64 + 4);
      const float4 l1 = *(const float4*)(hr + T * 64 + 32);
      const float4 h1 = *(const float4*)(hr + T * 64 + 36);
      const s8v b0 = *(const s8v*)(Bfrag + ((size_t)((T + 2) * 2 + 0) * 64 + lane) * 8);
      const s8v b1 = *(const s8v*)(Bfrag + ((size_t)((T + 2) * 2 + 1) * 64 + lane) * 8);
      acc = __builtin_amdgcn_mfma_f32_16x16x32_bf16(pack_bf16x8(l0, h0), b0, acc, 0, 0, 0);
      acc = __builtin_amdgcn_mfma_f32_16x16x32_bf16(pack_bf16x8(l1, h1), b1, acc, 0, 0, 0);
    }

    // scatter C (angles): lane holds rows m0+(lane>>4)*4+r, col lane&15
#pragma unroll
    for (int r = 0; r < 4; ++r)
      angL[(m0 + (lane >> 4) * 4 + r) * 17 + (lane & 15)] = acc[r];
  }
  __syncthreads();

  // ---- Phase 2: quantum sim (thread = (row = tid&63, gate = wv)) ----
  {
    const int row = tid & 63;
    const float* pbg = (wv == 0) ? pbF : (wv == 1) ? pbI : (wv == 2) ? pbO : pbC;
    float ang[4];
#pragma unroll
    for (int j = 0; j < 4; ++j) ang[j] = angL[row * 17 + wv * 4 + j] + pbg[j];

    float cs[4], sn[4];
#pragma unroll
    for (int j = 0; j < 4; j++) __sincosf(ang[j] * 0.5f, &sn[j], &cs[j]);
    float psi[16];
#pragma unroll
    for (int c16 = 0; c16 < 16; c16++) {
      float p = ((c16 & 8) ? sn[0] : cs[0]);
      p *= ((c16 & 4) ? sn[1] : cs[1]);
      p *= ((c16 & 2) ? sn[2] : cs[2]);
      p *= ((c16 & 1) ? sn[3] : cs[3]);
      psi[c16] = p;
    }
    const float2* Ug = U + wv * 256;
    float q0 = 0.f, q1 = 0.f, q2 = 0.f, q3 = 0.f;
#pragma unroll
    for (int m = 0; m < 16; m++) {
      float ssr = 0.f, ssi = 0.f;
#pragma unroll
      for (int c16 = 0; c16 < 16; c16++) {
        const float2 u = Ug[m * 16 + c16];
        ssr += u.x * psi[c16];
        ssi += u.y * psi[c16];
      }
      const float p = ssr * ssr + ssi * ssi;
      q0 = (m & 8) ? q0 - p : q0 + p;
      q1 = (m & 4) ? q1 - p : q1 + p;
      q2 = (m & 2) ? q2 - p : q2 + p;
      q3 = (m & 1) ? q3 - p : q3 + p;
    }
    *(float4*)&qL[row * 20 + wv * 4] = make_float4(q0, q1, q2, q3);
  }
  __syncthreads();

  // ---- Phase 3: LSTM expansion for these 64 rows ----
  {
    const int h0 = tid * 2;             // 2 consecutive h-positions

    float4 wF[2], wI[2], wO[2], wC[2];
    float bFv[2], bIv[2], bOv[2], bCv[2];
#pragma unroll
    for (int hh = 0; hh < 2; ++hh) {
      const int hp = h0 + hh;
      wF[hh] = *(const float4*)(lwF + (size_t)hp * 4);
      wI[hh] = *(const float4*)(lwI + (size_t)hp * 4);
      wO[hh] = *(const float4*)(lwO + (size_t)hp * 4);
      wC[hh] = *(const float4*)(lwC + (size_t)hp * 4);
      bFv[hh] = lbF[hp]; bIv[hh] = lbI[hp]; bOv[hh] = lbO[hp]; bCv[hh] = lbC[hp];
    }

#pragma unroll 2
    for (int it = 0; it < 64; ++it) {
      const size_t r = rb + it;
      const float* q = &qL[it * 20];          // wave-uniform -> broadcast ds_read
      const float4 qF = *(const float4*)(q);
      const float4 qI = *(const float4*)(q + 4);
      const float4 qO = *(const float4*)(q + 8);
      const float4 qC = *(const float4*)(q + 12);

      const f2v cp = __builtin_nontemporal_load(
          (const f2v*)(cprev + r * HIDDENN + h0));
      float hn[2], cn[2];
#pragma unroll
      for (int hh = 0; hh < 2; ++hh) {
        const float pf = bFv[hh] + wF[hh].x * qF.x + wF[hh].y * qF.y + wF[hh].z * qF.z + wF[hh].w * qF.w;
        const float pi = bIv[hh] + wI[hh].x * qI.x + wI[hh].y * qI.y + wI[hh].z * qI.z + wI[hh].w * qI.w;
        const float po = bOv[hh] + wO[hh].x * qO.x + wO[hh].y * qO.y + wO[hh].z * qO.z + wO[hh].w * qO.w;
        const float pg = bCv[hh] + wC[hh].x * qC.x + wC[hh].y * qC.y + wC[hh].z * qC.z + wC[hh].w * qC.w;
        const float f  = sigmf(pf);
        const float ii = sigmf(pi);
        const float oo = sigmf(po);
        const float gg = tanhfast(pg);
        const float cc = f * cp[hh] + ii * gg;
        cn[hh] = cc;
        hn[hh] = oo * tanhfast(cc);
      }
      f2v hv; hv[0] = hn[0]; hv[1] = hn[1];
      f2v cv; cv[0] = cn[0]; cv[1] = cn[1];
      __builtin_nontemporal_store(hv, (f2v*)(out + r * HIDDENN + h0));
      __builtin_nontemporal_store(cv,
          (f2v*)(out + (size_t)BATCHN * HIDDENN + r * HIDDENN + h0));
    }
  }
}

// ---------------------------------------------------------------------------
extern "C" void kernel_launch(void* const* d_in, const int* in_sizes, int n_in,
                              void* d_out, int out_size, void* d_ws, size_t ws_size,
                              hipStream_t stream) {
  const float* x  = (const float*)d_in[0];
  const float* h  = (const float*)d_in[1];
  const float* c  = (const float*)d_in[2];
  const float* pwF = (const float*)d_in[3];
  const float* pbF = (const float*)d_in[4];
  const float* qwF = (const float*)d_in[5];
  const float* lwF = (const float*)d_in[6];
  const float* lbF = (const float*)d_in[7];
  const float* pwI = (const float*)d_in[8];
  const float* pbI = (const float*)d_in[9];
  const float* qwI = (const float*)d_in[10];
  const float* lwI = (const float*)d_in[11];
  const float* lbI = (const float*)d_in[12];
  const float* pwO = (const float*)d_in[13];
  const float* pbO = (const float*)d_in[14];
  const float* qwO = (const float*)d_in[15];
  const float* lwO = (const float*)d_in[16];
  const float* lbO = (const float*)d_in[17];
  const float* pwC = (const float*)d_in[18];
  const float* pbC = (const float*)d_in[19];
  const float* qwC = (const float*)d_in[20];
  const float* lwC = (const float*)d_in[21];
  const float* lbC = (const float*)d_in[22];

  float2* U = (float2*)d_ws;                                   // 8 KB
  unsigned short* Bfrag = (unsigned short*)((char*)d_ws + 8192); // 20 KB

  k_prologue<<<dim3(1), dim3(256), 0, stream>>>(qwF, qwI, qwO, qwC,
                                                pwF, pwI, pwO, pwC, U, Bfrag);
  k_fused<<<dim3(BATCHN / 64), dim3(256), 0, stream>>>(
      x, h, pbF, pbI, pbO, pbC, U, Bfrag, c,
      lwF, lbF, lwI, lbI, lwO, lbO, lwC, lbC, (float*)d_out);
}

// Round 13
// 138.019 us; speedup vs baseline: 1.2324x; 1.2324x over previous
//
#include <hip/hip_runtime.h>
#include <math.h>

#define BATCHN 65536
#define INPUTN 128
#define HIDDENN 512
#define CATN 640
#define ROWS_LSTM 32

typedef float f2v __attribute__((ext_vector_type(2)));
typedef float f4v __attribute__((ext_vector_type(4)));
typedef short s8v __attribute__((ext_vector_type(8)));

__device__ __forceinline__ unsigned short f2bf_rne(float f) {
  unsigned u = __float_as_uint(f);
  u += 0x7fffu + ((u >> 16) & 1u);
  return (unsigned short)(u >> 16);
}

// pack 8 fp32 -> 8 bf16 (RNE) in MFMA fragment order
__device__ __forceinline__ s8v pack_bf16x8(float4 lo, float4 hi) {
  union { s8v s; unsigned u[4]; } r;
  asm("v_cvt_pk_bf16_f32 %0, %1, %2" : "=v"(r.u[0]) : "v"(lo.x), "v"(lo.y));
  asm("v_cvt_pk_bf16_f32 %0, %1, %2" : "=v"(r.u[1]) : "v"(lo.z), "v"(lo.w));
  asm("v_cvt_pk_bf16_f32 %0, %1, %2" : "=v"(r.u[2]) : "v"(hi.x), "v"(hi.y));
  asm("v_cvt_pk_bf16_f32 %0, %1, %2" : "=v"(r.u[3]) : "v"(hi.z), "v"(hi.w));
  return r.s;
}

// ---------------------------------------------------------------------------
// Prologue (1 block): (a) threads 0..63 build the fixed 16x16 unitary U_g per
// gate; (b) pack projection weights into bf16 MFMA B-fragments in lane order:
// Bfrag[s][lane] = B[k = s*32 + (lane>>4)*8 + j][n = lane&15], where
// B[k][n] = pw_{gate=n>>2}[(n&3)*640 + k].  20 KB, L2-hot. (verified v10/v11)
// ---------------------------------------------------------------------------
__global__ void k_prologue(const float* __restrict__ qwF, const float* __restrict__ qwI,
                           const float* __restrict__ qwO, const float* __restrict__ qwC,
                           const float* __restrict__ pwF, const float* __restrict__ pwI,
                           const float* __restrict__ pwO, const float* __restrict__ pwC,
                           float2* __restrict__ U, unsigned short* __restrict__ Bfrag) {
  const int t = threadIdx.x;
  if (t < 64) {
    int g = t >> 4, col = t & 15;
    const float* qw = (g == 0) ? qwF : (g == 1) ? qwI : (g == 2) ? qwO : qwC;

    float sr[16], si[16];
#pragma unroll
    for (int i = 0; i < 16; i++) { sr[i] = (i == col) ? 1.f : 0.f; si[i] = 0.f; }

#pragma unroll
    for (int l = 0; l < 2; l++) {
#pragma unroll
      for (int j = 0; j < 4; j++) {
        const int bc = 8 >> j;
        const int bt = 8 >> ((j + 1) & 3);
        float tr[16], ti[16];
#pragma unroll
        for (int i = 0; i < 16; i++) {
          int src = (i & bc) ? (i ^ bt) : i;
          tr[i] = sr[src]; ti[i] = si[src];
        }
#pragma unroll
        for (int i = 0; i < 16; i++) { sr[i] = tr[i]; si[i] = ti[i]; }
      }
#pragma unroll
      for (int j = 0; j < 4; j++) {
        const int bit = 8 >> j;
        const float thx = qw[(l * 4 + j) * 3 + 0] * 0.5f;
        const float thy = qw[(l * 4 + j) * 3 + 1] * 0.5f;
        const float thz = qw[(l * 4 + j) * 3 + 2] * 0.5f;
        float c, s;
        c = cosf(thx); s = sinf(thx);           // RX
#pragma unroll
        for (int i = 0; i < 16; i++) if (!(i & bit)) {
          const int k2 = i | bit;
          const float ar = sr[i], ai = si[i], br = sr[k2], bi = si[k2];
          sr[i]  = c * ar + s * bi;  si[i]  = c * ai - s * br;
          sr[k2] = c * br + s * ai;  si[k2] = c * bi - s * ar;
        }
        c = cosf(thy); s = sinf(thy);           // RY
#pragma unroll
        for (int i = 0; i < 16; i++) if (!(i & bit)) {
          const int k2 = i | bit;
          const float ar = sr[i], ai = si[i], br = sr[k2], bi = si[k2];
          sr[i]  = c * ar - s * br;  si[i]  = c * ai - s * bi;
          sr[k2] = s * ar + c * br;  si[k2] = s * ai + c * bi;
        }
        c = cosf(thz); s = sinf(thz);           // RZ
#pragma unroll
        for (int i = 0; i < 16; i++) if (!(i & bit)) {
          const int k2 = i | bit;
          const float ar = sr[i], ai = si[i], br = sr[k2], bi = si[k2];
          sr[i]  = c * ar + s * ai;  si[i]  = c * ai - s * ar;
          sr[k2] = c * br - s * bi;  si[k2] = c * bi + s * br;
        }
      }
    }
#pragma unroll
    for (int m = 0; m < 16; m++)
      U[(g * 16 + m) * 16 + col] = make_float2(sr[m], si[m]);
  }

  // B fragments: 20 k-steps x 64 lanes
  for (int e = t; e < 20 * 64; e += 256) {
    const int s = e >> 6, l = e & 63;
    const int n = l & 15, kb = l >> 4;
    const int gate = n >> 2, orow = n & 3;
    const float* pw = (gate == 0) ? pwF : (gate == 1) ? pwI : (gate == 2) ? pwO : pwC;
    const int k0 = s * 32 + kb * 8;
    unsigned short* dst = Bfrag + (size_t)e * 8;
#pragma unroll
    for (int j = 0; j < 8; ++j) dst[j] = f2bf_rne(pw[orow * CATN + k0 + j]);
  }
}

// ---------------------------------------------------------------------------
// Kernel 1 (v13): one WAVE per block, 16 rows per block, 4096 blocks.
// Same verified v11 MFMA math (A-fragments direct from global, prepacked
// L2-hot B-fragments, 20 x mfma_16x16x32_bf16 over K=640), but the grid is
// now a stream of small staggered blocks (~16 waves/CU avg, cap ~32) instead
// of 4 lockstep 4-wave blocks per CU -- no convoy, no cross-wave barriers.
// Sim phase: thread = (row = lane&15, gate = lane>>4), exactly 64 lanes.
// ---------------------------------------------------------------------------
__global__ __launch_bounds__(64) void k_proj_q(
    const float* __restrict__ x, const float* __restrict__ hprev,
    const float* __restrict__ pbF, const float* __restrict__ pbI,
    const float* __restrict__ pbO, const float* __restrict__ pbC,
    const float2* __restrict__ U, const unsigned short* __restrict__ Bfrag,
    float* __restrict__ qv) {
  __shared__ float angL[16 * 17];
  const int lane = threadIdx.x;
  const size_t rb = (size_t)blockIdx.x * 16;
  const int mr = lane & 15;             // A row within tile
  const int kb = lane >> 4;             // k-block 0..3
  const size_t arow = rb + mr;

  f4v acc = {0.f, 0.f, 0.f, 0.f};

  // x tiles: T = 0,1  (k = T*64 .. T*64+63)
  const float* xr = x + arow * INPUTN + kb * 8;
#pragma unroll
  for (int T = 0; T < 2; ++T) {
    const float4 l0 = *(const float4*)(xr + T * 64);
    const float4 h0 = *(const float4*)(xr + T * 64 + 4);
    const float4 l1 = *(const float4*)(xr + T * 64 + 32);
    const float4 h1 = *(const float4*)(xr + T * 64 + 36);
    const s8v b0 = *(const s8v*)(Bfrag + ((size_t)(T * 2 + 0) * 64 + lane) * 8);
    const s8v b1 = *(const s8v*)(Bfrag + ((size_t)(T * 2 + 1) * 64 + lane) * 8);
    acc = __builtin_amdgcn_mfma_f32_16x16x32_bf16(pack_bf16x8(l0, h0), b0, acc, 0, 0, 0);
    acc = __builtin_amdgcn_mfma_f32_16x16x32_bf16(pack_bf16x8(l1, h1), b1, acc, 0, 0, 0);
  }
  // h tiles: T = 0..7  (global k = 128 + T*64)
  const float* hr = hprev + arow * HIDDENN + kb * 8;
#pragma unroll 2
  for (int T = 0; T < 8; ++T) {
    const float4 l0 = *(const float4*)(hr + T * 64);
    const float4 h0 = *(const float4*)(hr + T * 64 + 4);
    const float4 l1 = *(const float4*)(hr + T * 64 + 32);
    const float4 h1 = *(const float4*)(hr + T * 64 + 36);
    const s8v b0 = *(const s8v*)(Bfrag + ((size_t)((T + 2) * 2 + 0) * 64 + lane) * 8);
    const s8v b1 = *(const s8v*)(Bfrag + ((size_t)((T + 2) * 2 + 1) * 64 + lane) * 8);
    acc = __builtin_amdgcn_mfma_f32_16x16x32_bf16(pack_bf16x8(l0, h0), b0, acc, 0, 0, 0);
    acc = __builtin_amdgcn_mfma_f32_16x16x32_bf16(pack_bf16x8(l1, h1), b1, acc, 0, 0, 0);
  }

  // scatter C (angles) to LDS: lane holds rows (lane>>4)*4+r, col lane&15
#pragma unroll
  for (int r = 0; r < 4; ++r)
    angL[((lane >> 4) * 4 + r) * 17 + (lane & 15)] = acc[r];
  __syncthreads();        // single-wave block: compiles to a cheap waitcnt

  // sim phase: thread = (row = lane&15, gate = lane>>4)
  const int row = lane & 15;
  const int g = lane >> 4;
  const float* pbg = (g == 0) ? pbF : (g == 1) ? pbI : (g == 2) ? pbO : pbC;
  float ang[4];
#pragma unroll
  for (int j = 0; j < 4; ++j) ang[j] = angL[row * 17 + g * 4 + j] + pbg[j];

  float cs[4], sn[4];
#pragma unroll
  for (int j = 0; j < 4; j++) __sincosf(ang[j] * 0.5f, &sn[j], &cs[j]);
  float psi[16];
#pragma unroll
  for (int c16 = 0; c16 < 16; c16++) {
    float p = ((c16 & 8) ? sn[0] : cs[0]);
    p *= ((c16 & 4) ? sn[1] : cs[1]);
    p *= ((c16 & 2) ? sn[2] : cs[2]);
    p *= ((c16 & 1) ? sn[3] : cs[3]);
    psi[c16] = p;
  }
  const float2* Ug = U + g * 256;
  float q0 = 0.f, q1 = 0.f, q2 = 0.f, q3 = 0.f;
#pragma unroll
  for (int m = 0; m < 16; m++) {
    float ssr = 0.f, ssi = 0.f;
#pragma unroll
    for (int c16 = 0; c16 < 16; c16++) {
      const float2 u = Ug[m * 16 + c16];
      ssr += u.x * psi[c16];
      ssi += u.y * psi[c16];
    }
    const float p = ssr * ssr + ssi * ssi;
    q0 = (m & 8) ? q0 - p : q0 + p;
    q1 = (m & 4) ? q1 - p : q1 + p;
    q2 = (m & 2) ? q2 - p : q2 + p;
    q3 = (m & 1) ? q3 - p : q3 + p;
  }
  *(float4*)(qv + (rb + row) * 16 + g * 4) = make_float4(q0, q1, q2, q3);
}

// ---------------------------------------------------------------------------
// Kernel 2: LSTM expansion (unchanged, proven). Thread owns 2 consecutive
// h-positions -> float2 nontemporal streaming; weights/biases register-
// resident; q block-uniform -> scalar loads.
// ---------------------------------------------------------------------------
__device__ __forceinline__ float sigmf(float v) {
  return __builtin_amdgcn_rcpf(1.f + __expf(-v));
}
__device__ __forceinline__ float tanhfast(float v) {
  return 1.f - 2.f * __builtin_amdgcn_rcpf(__expf(2.f * v) + 1.f);
}

__global__ __launch_bounds__(256) void k_lstm(
    const float* __restrict__ qv, const float* __restrict__ cprev,
    const float* __restrict__ lwF, const float* __restrict__ lbF,
    const float* __restrict__ lwI, const float* __restrict__ lbI,
    const float* __restrict__ lwO, const float* __restrict__ lbO,
    const float* __restrict__ lwC, const float* __restrict__ lbC,
    float* __restrict__ out) {
  const int tid = threadIdx.x;
  const int h0 = tid * 2;
  const int rb = blockIdx.x * ROWS_LSTM;

  float4 wF[2], wI[2], wO[2], wC[2];
  float bFv[2], bIv[2], bOv[2], bCv[2];
#pragma unroll
  for (int hh = 0; hh < 2; ++hh) {
    const int hp = h0 + hh;
    wF[hh] = *(const float4*)(lwF + (size_t)hp * 4);
    wI[hh] = *(const float4*)(lwI + (size_t)hp * 4);
    wO[hh] = *(const float4*)(lwO + (size_t)hp * 4);
    wC[hh] = *(const float4*)(lwC + (size_t)hp * 4);
    bFv[hh] = lbF[hp]; bIv[hh] = lbI[hp]; bOv[hh] = lbO[hp]; bCv[hh] = lbC[hp];
  }

#pragma unroll 2
  for (int it = 0; it < ROWS_LSTM; ++it) {
    const int r = rb + it;
    const float* q = qv + (size_t)r * 16;
    const float4 qF = *(const float4*)(q);
    const float4 qI = *(const float4*)(q + 4);
    const float4 qO = *(const float4*)(q + 8);
    const float4 qC = *(const float4*)(q + 12);

    const f2v cp = __builtin_nontemporal_load(
        (const f2v*)(cprev + (size_t)r * HIDDENN + h0));
    float hn[2], cn[2];
#pragma unroll
    for (int hh = 0; hh < 2; ++hh) {
      const float pf = bFv[hh] + wF[hh].x * qF.x + wF[hh].y * qF.y + wF[hh].z * qF.z + wF[hh].w * qF.w;
      const float pi = bIv[hh] + wI[hh].x * qI.x + wI[hh].y * qI.y + wI[hh].z * qI.z + wI[hh].w * qI.w;
      const float po = bOv[hh] + wO[hh].x * qO.x + wO[hh].y * qO.y + wO[hh].z * qO.z + wO[hh].w * qO.w;
      const float pg = bCv[hh] + wC[hh].x * qC.x + wC[hh].y * qC.y + wC[hh].z * qC.z + wC[hh].w * qC.w;
      const float f  = sigmf(pf);
      const float ii = sigmf(pi);
      const float oo = sigmf(po);
      const float gg = tanhfast(pg);
      const float cc = f * cp[hh] + ii * gg;
      cn[hh] = cc;
      hn[hh] = oo * tanhfast(cc);
    }
    f2v hv; hv[0] = hn[0]; hv[1] = hn[1];
    f2v cv; cv[0] = cn[0]; cv[1] = cn[1];
    __builtin_nontemporal_store(hv, (f2v*)(out + (size_t)r * HIDDENN + h0));
    __builtin_nontemporal_store(cv,
        (f2v*)(out + (size_t)BATCHN * HIDDENN + (size_t)r * HIDDENN + h0));
  }
}

// ---------------------------------------------------------------------------
extern "C" void kernel_launch(void* const* d_in, const int* in_sizes, int n_in,
                              void* d_out, int out_size, void* d_ws, size_t ws_size,
                              hipStream_t stream) {
  const float* x  = (const float*)d_in[0];
  const float* h  = (const float*)d_in[1];
  const float* c  = (const float*)d_in[2];
  const float* pwF = (const float*)d_in[3];
  const float* pbF = (const float*)d_in[4];
  const float* qwF = (const float*)d_in[5];
  const float* lwF = (const float*)d_in[6];
  const float* lbF = (const float*)d_in[7];
  const float* pwI = (const float*)d_in[8];
  const float* pbI = (const float*)d_in[9];
  const float* qwI = (const float*)d_in[10];
  const float* lwI = (const float*)d_in[11];
  const float* lbI = (const float*)d_in[12];
  const float* pwO = (const float*)d_in[13];
  const float* pbO = (const float*)d_in[14];
  const float* qwO = (const float*)d_in[15];
  const float* lwO = (const float*)d_in[16];
  const float* lbO = (const float*)d_in[17];
  const float* pwC = (const float*)d_in[18];
  const float* pbC = (const float*)d_in[19];
  const float* qwC = (const float*)d_in[20];
  const float* lwC = (const float*)d_in[21];
  const float* lbC = (const float*)d_in[22];

  float* ws = (float*)d_ws;
  float* qv = ws;                                    // 65536*16 f   (4 MB)
  float2* U = (float2*)(ws + (size_t)BATCHN * 16);   // 1024 float2  (8 KB)
  unsigned short* Bfrag =
      (unsigned short*)(ws + (size_t)BATCHN * 16 + 2048);  // 20*64*8 bf16 (20 KB)

  k_prologue<<<dim3(1), dim3(256), 0, stream>>>(qwF, qwI, qwO, qwC,
                                                pwF, pwI, pwO, pwC, U, Bfrag);
  k_proj_q<<<dim3(BATCHN / 16), dim3(64), 0, stream>>>(x, h, pbF, pbI, pbO, pbC,
                                                       U, Bfrag, qv);
  k_lstm<<<dim3(BATCHN / ROWS_LSTM), dim3(256), 0, stream>>>(qv, c, lwF, lbF, lwI, lbI,
                                                             lwO, lbO, lwC, lbC,
                                                             (float*)d_out);
}

// Round 14
// 137.581 us; speedup vs baseline: 1.2363x; 1.0032x over previous
//
#include <hip/hip_runtime.h>
#include <math.h>

#define BATCHN 65536
#define INPUTN 128
#define HIDDENN 512
#define CATN 640
#define ROWS_LSTM 32

typedef float f2v __attribute__((ext_vector_type(2)));
typedef float f4v __attribute__((ext_vector_type(4)));
typedef short s8v __attribute__((ext_vector_type(8)));

__device__ __forceinline__ unsigned short f2bf_rne(float f) {
  unsigned u = __float_as_uint(f);
  u += 0x7fffu + ((u >> 16) & 1u);
  return (unsigned short)(u >> 16);
}

// pack 8 fp32 -> 8 bf16 (RNE) in MFMA fragment order
__device__ __forceinline__ s8v pack_bf16x8(float4 lo, float4 hi) {
  union { s8v s; unsigned u[4]; } r;
  asm("v_cvt_pk_bf16_f32 %0, %1, %2" : "=v"(r.u[0]) : "v"(lo.x), "v"(lo.y));
  asm("v_cvt_pk_bf16_f32 %0, %1, %2" : "=v"(r.u[1]) : "v"(lo.z), "v"(lo.w));
  asm("v_cvt_pk_bf16_f32 %0, %1, %2" : "=v"(r.u[2]) : "v"(hi.x), "v"(hi.y));
  asm("v_cvt_pk_bf16_f32 %0, %1, %2" : "=v"(r.u[3]) : "v"(hi.z), "v"(hi.w));
  return r.s;
}

// ---------------------------------------------------------------------------
// Prologue (1 block): (a) threads 0..63 build the fixed 16x16 unitary U_g per
// gate; (b) pack projection weights into bf16 MFMA B-fragments in lane order:
// Bfrag[s][lane] = B[k = s*32 + (lane>>4)*8 + j][n = lane&15], where
// B[k][n] = pw_{gate=n>>2}[(n&3)*640 + k].  20 KB, L2-hot. (verified v10-v13)
// ---------------------------------------------------------------------------
__global__ void k_prologue(const float* __restrict__ qwF, const float* __restrict__ qwI,
                           const float* __restrict__ qwO, const float* __restrict__ qwC,
                           const float* __restrict__ pwF, const float* __restrict__ pwI,
                           const float* __restrict__ pwO, const float* __restrict__ pwC,
                           float2* __restrict__ U, unsigned short* __restrict__ Bfrag) {
  const int t = threadIdx.x;
  if (t < 64) {
    int g = t >> 4, col = t & 15;
    const float* qw = (g == 0) ? qwF : (g == 1) ? qwI : (g == 2) ? qwO : qwC;

    float sr[16], si[16];
#pragma unroll
    for (int i = 0; i < 16; i++) { sr[i] = (i == col) ? 1.f : 0.f; si[i] = 0.f; }

#pragma unroll
    for (int l = 0; l < 2; l++) {
#pragma unroll
      for (int j = 0; j < 4; j++) {
        const int bc = 8 >> j;
        const int bt = 8 >> ((j + 1) & 3);
        float tr[16], ti[16];
#pragma unroll
        for (int i = 0; i < 16; i++) {
          int src = (i & bc) ? (i ^ bt) : i;
          tr[i] = sr[src]; ti[i] = si[src];
        }
#pragma unroll
        for (int i = 0; i < 16; i++) { sr[i] = tr[i]; si[i] = ti[i]; }
      }
#pragma unroll
      for (int j = 0; j < 4; j++) {
        const int bit = 8 >> j;
        const float thx = qw[(l * 4 + j) * 3 + 0] * 0.5f;
        const float thy = qw[(l * 4 + j) * 3 + 1] * 0.5f;
        const float thz = qw[(l * 4 + j) * 3 + 2] * 0.5f;
        float c, s;
        c = cosf(thx); s = sinf(thx);           // RX
#pragma unroll
        for (int i = 0; i < 16; i++) if (!(i & bit)) {
          const int k2 = i | bit;
          const float ar = sr[i], ai = si[i], br = sr[k2], bi = si[k2];
          sr[i]  = c * ar + s * bi;  si[i]  = c * ai - s * br;
          sr[k2] = c * br + s * ai;  si[k2] = c * bi - s * ar;
        }
        c = cosf(thy); s = sinf(thy);           // RY
#pragma unroll
        for (int i = 0; i < 16; i++) if (!(i & bit)) {
          const int k2 = i | bit;
          const float ar = sr[i], ai = si[i], br = sr[k2], bi = si[k2];
          sr[i]  = c * ar - s * br;  si[i]  = c * ai - s * bi;
          sr[k2] = s * ar + c * br;  si[k2] = s * ai + c * bi;
        }
        c = cosf(thz); s = sinf(thz);           // RZ
#pragma unroll
        for (int i = 0; i < 16; i++) if (!(i & bit)) {
          const int k2 = i | bit;
          const float ar = sr[i], ai = si[i], br = sr[k2], bi = si[k2];
          sr[i]  = c * ar + s * ai;  si[i]  = c * ai - s * ar;
          sr[k2] = c * br - s * bi;  si[k2] = c * bi + s * br;
        }
      }
    }
#pragma unroll
    for (int m = 0; m < 16; m++)
      U[(g * 16 + m) * 16 + col] = make_float2(sr[m], si[m]);
  }

  // B fragments: 20 k-steps x 64 lanes
  for (int e = t; e < 20 * 64; e += 256) {
    const int s = e >> 6, l = e & 63;
    const int n = l & 15, kb = l >> 4;
    const int gate = n >> 2, orow = n & 3;
    const float* pw = (gate == 0) ? pwF : (gate == 1) ? pwI : (gate == 2) ? pwO : pwC;
    const int k0 = s * 32 + kb * 8;
    unsigned short* dst = Bfrag + (size_t)e * 8;
#pragma unroll
    for (int j = 0; j < 8; ++j) dst[j] = f2bf_rne(pw[orow * CATN + k0 + j]);
  }
}

// ---------------------------------------------------------------------------
// Kernel 1 (v14 = v13 + deeper load pipeline): one WAVE per block, 16 rows,
// 4096 blocks (16 waves/CU — capped by total work). The h-tile loop unroll
// goes 2 -> 4 so ~16-24 loads stay in flight per wave (v13's ~8-12 left the
// memory system under-subscribed at 400-900 cy latency). No other changes.
// ---------------------------------------------------------------------------
__global__ __launch_bounds__(64) void k_proj_q(
    const float* __restrict__ x, const float* __restrict__ hprev,
    const float* __restrict__ pbF, const float* __restrict__ pbI,
    const float* __restrict__ pbO, const float* __restrict__ pbC,
    const float2* __restrict__ U, const unsigned short* __restrict__ Bfrag,
    float* __restrict__ qv) {
  __shared__ float angL[16 * 17];
  const int lane = threadIdx.x;
  const size_t rb = (size_t)blockIdx.x * 16;
  const int mr = lane & 15;             // A row within tile
  const int kb = lane >> 4;             // k-block 0..3
  const size_t arow = rb + mr;

  f4v acc = {0.f, 0.f, 0.f, 0.f};

  // x tiles: T = 0,1  (k = T*64 .. T*64+63)
  const float* xr = x + arow * INPUTN + kb * 8;
#pragma unroll
  for (int T = 0; T < 2; ++T) {
    const float4 l0 = *(const float4*)(xr + T * 64);
    const float4 h0 = *(const float4*)(xr + T * 64 + 4);
    const float4 l1 = *(const float4*)(xr + T * 64 + 32);
    const float4 h1 = *(const float4*)(xr + T * 64 + 36);
    const s8v b0 = *(const s8v*)(Bfrag + ((size_t)(T * 2 + 0) * 64 + lane) * 8);
    const s8v b1 = *(const s8v*)(Bfrag + ((size_t)(T * 2 + 1) * 64 + lane) * 8);
    acc = __builtin_amdgcn_mfma_f32_16x16x32_bf16(pack_bf16x8(l0, h0), b0, acc, 0, 0, 0);
    acc = __builtin_amdgcn_mfma_f32_16x16x32_bf16(pack_bf16x8(l1, h1), b1, acc, 0, 0, 0);
  }
  // h tiles: T = 0..7  (global k = 128 + T*64); unroll 4 for load depth
  const float* hr = hprev + arow * HIDDENN + kb * 8;
#pragma unroll 4
  for (int T = 0; T < 8; ++T) {
    const float4 l0 = *(const float4*)(hr + T * 64);
    const float4 h0 = *(const float4*)(hr + T * 64 + 4);
    const float4 l1 = *(const float4*)(hr + T * 64 + 32);
    const float4 h1 = *(const float4*)(hr + T * 64 + 36);
    const s8v b0 = *(const s8v*)(Bfrag + ((size_t)((T + 2) * 2 + 0) * 64 + lane) * 8);
    const s8v b1 = *(const s8v*)(Bfrag + ((size_t)((T + 2) * 2 + 1) * 64 + lane) * 8);
    acc = __builtin_amdgcn_mfma_f32_16x16x32_bf16(pack_bf16x8(l0, h0), b0, acc, 0, 0, 0);
    acc = __builtin_amdgcn_mfma_f32_16x16x32_bf16(pack_bf16x8(l1, h1), b1, acc, 0, 0, 0);
  }

  // scatter C (angles) to LDS: lane holds rows (lane>>4)*4+r, col lane&15
#pragma unroll
  for (int r = 0; r < 4; ++r)
    angL[((lane >> 4) * 4 + r) * 17 + (lane & 15)] = acc[r];
  __syncthreads();        // single-wave block: cheap

  // sim phase: thread = (row = lane&15, gate = lane>>4)
  const int row = lane & 15;
  const int g = lane >> 4;
  const float* pbg = (g == 0) ? pbF : (g == 1) ? pbI : (g == 2) ? pbO : pbC;
  float ang[4];
#pragma unroll
  for (int j = 0; j < 4; ++j) ang[j] = angL[row * 17 + g * 4 + j] + pbg[j];

  float cs[4], sn[4];
#pragma unroll
  for (int j = 0; j < 4; j++) __sincosf(ang[j] * 0.5f, &sn[j], &cs[j]);
  float psi[16];
#pragma unroll
  for (int c16 = 0; c16 < 16; c16++) {
    float p = ((c16 & 8) ? sn[0] : cs[0]);
    p *= ((c16 & 4) ? sn[1] : cs[1]);
    p *= ((c16 & 2) ? sn[2] : cs[2]);
    p *= ((c16 & 1) ? sn[3] : cs[3]);
    psi[c16] = p;
  }
  const float2* Ug = U + g * 256;
  float q0 = 0.f, q1 = 0.f, q2 = 0.f, q3 = 0.f;
#pragma unroll
  for (int m = 0; m < 16; m++) {
    float ssr = 0.f, ssi = 0.f;
#pragma unroll
    for (int c16 = 0; c16 < 16; c16++) {
      const float2 u = Ug[m * 16 + c16];
      ssr += u.x * psi[c16];
      ssi += u.y * psi[c16];
    }
    const float p = ssr * ssr + ssi * ssi;
    q0 = (m & 8) ? q0 - p : q0 + p;
    q1 = (m & 4) ? q1 - p : q1 + p;
    q2 = (m & 2) ? q2 - p : q2 + p;
    q3 = (m & 1) ? q3 - p : q3 + p;
  }
  *(float4*)(qv + (rb + row) * 16 + g * 4) = make_float4(q0, q1, q2, q3);
}

// ---------------------------------------------------------------------------
// Kernel 2: LSTM expansion (unchanged, proven). Thread owns 2 consecutive
// h-positions -> float2 nontemporal streaming; weights/biases register-
// resident; q block-uniform -> scalar loads.
// ---------------------------------------------------------------------------
__device__ __forceinline__ float sigmf(float v) {
  return __builtin_amdgcn_rcpf(1.f + __expf(-v));
}
__device__ __forceinline__ float tanhfast(float v) {
  return 1.f - 2.f * __builtin_amdgcn_rcpf(__expf(2.f * v) + 1.f);
}

__global__ __launch_bounds__(256) void k_lstm(
    const float* __restrict__ qv, const float* __restrict__ cprev,
    const float* __restrict__ lwF, const float* __restrict__ lbF,
    const float* __restrict__ lwI, const float* __restrict__ lbI,
    const float* __restrict__ lwO, const float* __restrict__ lbO,
    const float* __restrict__ lwC, const float* __restrict__ lbC,
    float* __restrict__ out) {
  const int tid = threadIdx.x;
  const int h0 = tid * 2;
  const int rb = blockIdx.x * ROWS_LSTM;

  float4 wF[2], wI[2], wO[2], wC[2];
  float bFv[2], bIv[2], bOv[2], bCv[2];
#pragma unroll
  for (int hh = 0; hh < 2; ++hh) {
    const int hp = h0 + hh;
    wF[hh] = *(const float4*)(lwF + (size_t)hp * 4);
    wI[hh] = *(const float4*)(lwI + (size_t)hp * 4);
    wO[hh] = *(const float4*)(lwO + (size_t)hp * 4);
    wC[hh] = *(const float4*)(lwC + (size_t)hp * 4);
    bFv[hh] = lbF[hp]; bIv[hh] = lbI[hp]; bOv[hh] = lbO[hp]; bCv[hh] = lbC[hp];
  }

#pragma unroll 2
  for (int it = 0; it < ROWS_LSTM; ++it) {
    const int r = rb + it;
    const float* q = qv + (size_t)r * 16;
    const float4 qF = *(const float4*)(q);
    const float4 qI = *(const float4*)(q + 4);
    const float4 qO = *(const float4*)(q + 8);
    const float4 qC = *(const float4*)(q + 12);

    const f2v cp = __builtin_nontemporal_load(
        (const f2v*)(cprev + (size_t)r * HIDDENN + h0));
    float hn[2], cn[2];
#pragma unroll
    for (int hh = 0; hh < 2; ++hh) {
      const float pf = bFv[hh] + wF[hh].x * qF.x + wF[hh].y * qF.y + wF[hh].z * qF.z + wF[hh].w * qF.w;
      const float pi = bIv[hh] + wI[hh].x * qI.x + wI[hh].y * qI.y + wI[hh].z * qI.z + wI[hh].w * qI.w;
      const float po = bOv[hh] + wO[hh].x * qO.x + wO[hh].y * qO.y + wO[hh].z * qO.z + wO[hh].w * qO.w;
      const float pg = bCv[hh] + wC[hh].x * qC.x + wC[hh].y * qC.y + wC[hh].z * qC.z + wC[hh].w * qC.w;
      const float f  = sigmf(pf);
      const float ii = sigmf(pi);
      const float oo = sigmf(po);
      const float gg = tanhfast(pg);
      const float cc = f * cp[hh] + ii * gg;
      cn[hh] = cc;
      hn[hh] = oo * tanhfast(cc);
    }
    f2v hv; hv[0] = hn[0]; hv[1] = hn[1];
    f2v cv; cv[0] = cn[0]; cv[1] = cn[1];
    __builtin_nontemporal_store(hv, (f2v*)(out + (size_t)r * HIDDENN + h0));
    __builtin_nontemporal_store(cv,
        (f2v*)(out + (size_t)BATCHN * HIDDENN + (size_t)r * HIDDENN + h0));
  }
}

// ---------------------------------------------------------------------------
extern "C" void kernel_launch(void* const* d_in, const int* in_sizes, int n_in,
                              void* d_out, int out_size, void* d_ws, size_t ws_size,
                              hipStream_t stream) {
  const float* x  = (const float*)d_in[0];
  const float* h  = (const float*)d_in[1];
  const float* c  = (const float*)d_in[2];
  const float* pwF = (const float*)d_in[3];
  const float* pbF = (const float*)d_in[4];
  const float* qwF = (const float*)d_in[5];
  const float* lwF = (const float*)d_in[6];
  const float* lbF = (const float*)d_in[7];
  const float* pwI = (const float*)d_in[8];
  const float* pbI = (const float*)d_in[9];
  const float* qwI = (const float*)d_in[10];
  const float* lwI = (const float*)d_in[11];
  const float* lbI = (const float*)d_in[12];
  const float* pwO = (const float*)d_in[13];
  const float* pbO = (const float*)d_in[14];
  const float* qwO = (const float*)d_in[15];
  const float* lwO = (const float*)d_in[16];
  const float* lbO = (const float*)d_in[17];
  const float* pwC = (const float*)d_in[18];
  const float* pbC = (const float*)d_in[19];
  const float* qwC = (const float*)d_in[20];
  const float* lwC = (const float*)d_in[21];
  const float* lbC = (const float*)d_in[22];

  float* ws = (float*)d_ws;
  float* qv = ws;                                    // 65536*16 f   (4 MB)
  float2* U = (float2*)(ws + (size_t)BATCHN * 16);   // 1024 float2  (8 KB)
  unsigned short* Bfrag =
      (unsigned short*)(ws + (size_t)BATCHN * 16 + 2048);  // 20*64*8 bf16 (20 KB)

  k_prologue<<<dim3(1), dim3(256), 0, stream>>>(qwF, qwI, qwO, qwC,
                                                pwF, pwI, pwO, pwC, U, Bfrag);
  k_proj_q<<<dim3(BATCHN / 16), dim3(64), 0, stream>>>(x, h, pbF, pbI, pbO, pbC,
                                                       U, Bfrag, qv);
  k_lstm<<<dim3(BATCHN / ROWS_LSTM), dim3(256), 0, stream>>>(qv, c, lwF, lbF, lwI, lbI,
                                                             lwO, lbO, lwC, lbC,
                                                             (float*)d_out);
}